// Round 1
// 263.041 us; speedup vs baseline: 1.0952x; 1.0952x over previous
//
#include <hip/hip_runtime.h>
#include <hip/hip_bf16.h>

#define HH 96
#define WW 96
#define CC 21
#define NN (HH*WW)          // 9216
#define NELEM (NN*CC)       // 193536
#define RS 20               // blur radius: exp(-400/18)=2e-10 tail, negligible
#define NPAR (2*CC + CC*CC)
#define L2E 1.4426950408889634f
#define MSTEPS 24           // 24 m-rows per chunk (24x16 = 384 px)
#define NBB (36*24)         // 36 n-tiles (16x16) x 24 m-chunks (24x16)
#define NSTRIP 8            // 8 strips of 12 rows
#define NBLUR (CC*NSTRIP)   // 168 blur blocks
#define SROWS 12            // output rows per strip
#define TRUNC2 1936         // 44^2: exp(-0.5*44^2/64)=3e-7, below bf16 noise on K

typedef short bf16x8 __attribute__((ext_vector_type(8)));
typedef float f32x16 __attribute__((ext_vector_type(16)));

__device__ __forceinline__ float fexp2(float x) { return __builtin_amdgcn_exp2f(x); }
__device__ __forceinline__ float fexp(float x)  { return __builtin_amdgcn_exp2f(x * L2E); }

__device__ __forceinline__ short f2b(float f) {
    __hip_bfloat16 h = __float2bfloat16(f);
    short s; __builtin_memcpy(&s, &h, 2); return s;
}

// ---- dtype sniff: bf16 data never contains exp=0xFF bit patterns; fp32 data's
// low mantissa halves hit it ~0.4% of the time.
__global__ void k_sniff(const unsigned short* __restrict__ u16, int* __restrict__ flag) {
    __shared__ int sfound;
    if (threadIdx.x == 0) sfound = 0;
    __syncthreads();
    int found = 0;
    for (int i = threadIdx.x; i < NELEM; i += 1024) {
        unsigned v = u16[i];
        if ((v & 0x7F80u) == 0x7F80u) found = 1;
    }
    if (found) sfound = 1;
    __syncthreads();
    if (threadIdx.x == 0) *flag = sfound;   // 1 = fp32 inputs, 0 = bf16
}

// Fused prep: convert u -> uf (fp32 n-major), softmax -> pT (bf16 c-major),
// build featx, convert params, zero bil. Grid 36x256 (one thread per pixel).
__global__ __launch_bounds__(256) void k_prep(
    const void* __restrict__ u, const void* __restrict__ img,
    const void* __restrict__ wS, const void* __restrict__ wB,
    const void* __restrict__ compat, const int* __restrict__ flag,
    float* __restrict__ uf, float* __restrict__ featx, float* __restrict__ par,
    float* __restrict__ bil, __hip_bfloat16* __restrict__ pT)
{
    const int f = *flag;
    const int tid = threadIdx.x;
    const int n = blockIdx.x * 256 + tid;

    if (blockIdx.x == 0) {
        for (int i = tid; i < NPAR; i += 256) {
            const void* src; int j;
            if (i < CC)        { src = wS;     j = i; }
            else if (i < 2*CC) { src = wB;     j = i - CC; }
            else               { src = compat; j = i - 2*CC; }
            par[i] = f ? ((const float*)src)[j]
                       : __bfloat162float(((const __hip_bfloat16*)src)[j]);
        }
    }

    // featx[n]: log2-prescaled symmetric bilateral features
    {
        float c0, c1, c2;
        if (f) { const float* p = (const float*)img;
                 c0 = p[3*n]; c1 = p[3*n+1]; c2 = p[3*n+2]; }
        else   { const __hip_bfloat16* p = (const __hip_bfloat16*)img;
                 c0 = __bfloat162float(p[3*n]); c1 = __bfloat162float(p[3*n+1]);
                 c2 = __bfloat162float(p[3*n+2]); }
        float ym = (float)(n / WW), xm = (float)(n % WW);
        const float sc = 0.15014029f;   // sqrt(2*L2E/128)
        const float cf = 9.6089787f;    // sqrt(64*L2E)
        featx[8*n + 0] = -L2E * (fmaf(ym, ym, xm*xm) * 0.0078125f
                                 + 32.f * (c0*c0 + c1*c1 + c2*c2));
        featx[8*n + 1] = sc * ym;
        featx[8*n + 2] = sc * xm;
        featx[8*n + 3] = cf * c0;
        featx[8*n + 4] = cf * c1;
        featx[8*n + 5] = cf * c2;
        featx[8*n + 6] = 0.f;
        featx[8*n + 7] = 0.f;
    }

    float v[CC];
    float mx = -1e30f;
    #pragma unroll
    for (int c = 0; c < CC; c++) {
        float uv = f ? ((const float*)u)[n*CC + c]
                     : __bfloat162float(((const __hip_bfloat16*)u)[n*CC + c]);
        uf[n*CC + c] = uv;
        v[c] = uv;
        mx = fmaxf(mx, uv);
    }
    float s = 0.f;
    #pragma unroll
    for (int c = 0; c < CC; c++) { v[c] = fexp(v[c] - mx); s += v[c]; }
    float inv = 1.f / s;
    #pragma unroll
    for (int c = 0; c < CC; c++) {
        pT[(size_t)c*NN + n] = __float2bfloat16(v[c] * inv);
        bil[(size_t)c*NN + n] = 0.f;
    }
}

// Fused work kernel. Blocks [0, NBB): MFMA bilateral over 2D tiles with
// spatial truncation (theta_alpha=8 -> K < 3e-7 beyond 44px; skip those
// block pairs and m-rows entirely). Blocks [NBB, NBB+NBLUR): separable
// spatial blur (c-major, coalesced). Blur work hides behind bilateral.
__global__ __launch_bounds__(256) void k_work(
    const __hip_bfloat16* __restrict__ pT,   // [32][NN] bf16 (rows 21..31 garbage)
    const float* __restrict__ featx,         // [NN][8]
    float* __restrict__ bil,                 // [CC][NN] atomic accum
    float* __restrict__ s2T)                 // [CC][NN] spatial out
{
    __shared__ float smem[6176];             // bilateral: 3072; blur: 4992+1152
    const int tid = threadIdx.x;
    const int bid = blockIdx.x;

    if (bid < NBB) {
        // ---------------- bilateral: bil[c][n] += sum_m pT[c][m] * K(n,m)
        // n-tile: 16x16 pixels. m-chunk: 24 rows x 16 cols; each k-step is one
        // 16-px row segment (contiguous in pT => afrag layout unchanged).
        // D(32c x 32n) = A(32c x 16m) * B(16m x 32n), v_mfma_f32_32x32x16_bf16
        float* lds_h = smem;
        const int wv   = tid >> 6, lane = tid & 63;
        const int quad = lane >> 5, lid = lane & 31;

        const int nt = bid % 36, mc = bid / 36;
        const int ny0 = (nt / 6) * 16, nx0 = (nt % 6) * 16;
        const int my0 = (mc & 3) * 24, mx0 = (mc >> 2) * 16;

        // block-level truncation: min pixel gap between tiles
        const int dx = (mx0 > nx0 + 15) ? mx0 - (nx0 + 15)
                     : ((nx0 > mx0 + 15) ? nx0 - (mx0 + 15) : 0);
        {
            const int dy = (my0 > ny0 + 15) ? my0 - (ny0 + 15)
                         : ((ny0 > my0 + 23) ? ny0 - (my0 + 23) : 0);
            if (dy * dy + dx * dx > TRUNC2) return;
        }

        {   // stage featx chunk: [seg 0..23][16 px][8 floats]
            float4* dst = (float4*)lds_h;
            for (int i = tid; i < MSTEPS * 32; i += 256) {
                const int seg = i >> 5, off = i & 31;
                dst[i] = ((const float4*)(featx +
                          (size_t)((my0 + seg) * WW + mx0) * 8))[off];
            }
        }
        __syncthreads();

        const int row = lid >> 4, col = lid & 15;
        const int n0 = (ny0 + 4 * wv + row) * WW + nx0 + col;   // acc0 pixel
        const int n1 = n0 + 2 * WW;                             // acc1 pixel
        const float4 g0a = *(const float4*)(featx + (size_t)n0 * 8);
        const float4 g0b = *(const float4*)(featx + (size_t)n0 * 8 + 4);
        const float4 g1a = *(const float4*)(featx + (size_t)n1 * 8);
        const float4 g1b = *(const float4*)(featx + (size_t)n1 * 8 + 4);

        f32x16 acc0, acc1;
        #pragma unroll
        for (int r = 0; r < 16; r++) { acc0[r] = 0.f; acc1[r] = 0.f; }

        int mg = my0 * WW + mx0 + quad * 8;   // afrag global base
        #pragma unroll 1
        for (int step = 0; step < MSTEPS; step++, mg += WW) {
            // step-level truncation: this m-row vs n-tile rows (wave-uniform)
            const int ry = my0 + step;
            const int dys = (ry > ny0 + 15) ? ry - (ny0 + 15)
                          : ((ny0 > ry) ? ny0 - ry : 0);
            if (dys * dys + dx * dx > TRUNC2) continue;

            bf16x8 afrag = *(const bf16x8*)(pT + (size_t)lid * NN + mg);

            const float* h = lds_h + (step * 16 + quad * 8) * 8;
            float kb0[8], kb1[8];
            #pragma unroll
            for (int j = 0; j < 8; j++) {
                float4 ha = *(const float4*)(h + j * 8);
                float4 hb = *(const float4*)(h + j * 8 + 4);
                float s0 = g0a.x + ha.x;
                s0 = fmaf(g0a.y, ha.y, s0);
                s0 = fmaf(g0a.z, ha.z, s0);
                s0 = fmaf(g0a.w, ha.w, s0);
                s0 = fmaf(g0b.x, hb.x, s0);
                s0 = fmaf(g0b.y, hb.y, s0);
                kb0[j] = fexp2(s0);
                float s1 = g1a.x + ha.x;
                s1 = fmaf(g1a.y, ha.y, s1);
                s1 = fmaf(g1a.z, ha.z, s1);
                s1 = fmaf(g1a.w, ha.w, s1);
                s1 = fmaf(g1b.x, hb.x, s1);
                s1 = fmaf(g1b.y, hb.y, s1);
                kb1[j] = fexp2(s1);
            }
            bf16x8 b0, b1;
            #pragma unroll
            for (int j = 0; j < 8; j++) { b0[j] = f2b(kb0[j]); b1[j] = f2b(kb1[j]); }

            acc0 = __builtin_amdgcn_mfma_f32_32x32x16_bf16(afrag, b0, acc0, 0, 0, 0);
            acc1 = __builtin_amdgcn_mfma_f32_32x32x16_bf16(afrag, b1, acc1, 0, 0, 0);
        }

        // D layout: col(n) = lid, row(c) = (r&3) + 8*(r>>2) + 4*quad
        #pragma unroll
        for (int r = 0; r < 16; r++) {
            int c = (r & 3) + 8 * (r >> 2) + 4 * quad;
            if (c < CC) {
                atomicAdd(&bil[(size_t)c * NN + n0], acc0[r]);
                atomicAdd(&bil[(size_t)c * NN + n1], acc1[r]);
            }
        }
    } else {
        // ---------------- spatial blur, one (channel, 12-row strip) per block
        __shared__ float w_s[RS + 1];
        float* A  = smem;            // up to 52 rows x 96
        float* B2 = smem + 4992;     // 12 rows x 96

        const int b2 = bid - NBB;
        const int c = b2 % CC;
        const int strip = b2 / CC;
        const int y0 = strip * SROWS;
        const int ylo = (y0 - RS < 0) ? 0 : y0 - RS;
        const int yhi = (y0 + SROWS - 1 + RS > HH - 1) ? HH - 1 : y0 + SROWS - 1 + RS;
        const int nrows = yhi - ylo + 1;

        if (tid <= RS) w_s[tid] = fexp2(-(float)(tid*tid) * (L2E / 18.f));
        const __hip_bfloat16* src = pT + (size_t)c * NN + ylo * WW;
        for (int i = tid; i < nrows * WW; i += 256)
            A[i] = __bfloat162float(src[i]);
        __syncthreads();

        for (int i = tid; i < SROWS * WW; i += 256) {
            const int yo = y0 + i / WW;
            const int x  = i % WW;
            float acc = A[(yo - ylo) * WW + x];
            #pragma unroll
            for (int d = 1; d <= RS; d++) {
                float s = 0.f;
                if (yo - d >= 0)  s += A[(yo - d - ylo) * WW + x];
                if (yo + d < HH)  s += A[(yo + d - ylo) * WW + x];
                acc = fmaf(w_s[d], s, acc);
            }
            B2[i] = acc;
        }
        __syncthreads();

        for (int i = tid; i < SROWS * WW; i += 256) {
            const int r = i / WW, x = i % WW;
            float acc = B2[i];
            #pragma unroll
            for (int d = 1; d <= RS; d++) {
                float s = 0.f;
                if (x - d >= 0)  s += B2[r * WW + x - d];
                if (x + d < WW)  s += B2[r * WW + x + d];
                acc = fmaf(w_s[d], s, acc);
            }
            s2T[(size_t)c * NN + (y0 + r) * WW + x] = acc;
        }
    }
}

// Combine spatial+bilateral, compatibility, q-update, fused softmax -> pT.
// Re-zeroes bil. Last iter writes d_out instead.
__global__ __launch_bounds__(256) void k_update(
    float* __restrict__ bil, const float* __restrict__ s2T,
    const float* __restrict__ uf, const float* __restrict__ par,
    const int* __restrict__ flag,
    __hip_bfloat16* __restrict__ pT, void* __restrict__ out, int last)
{
    __shared__ float sc[CC*CC];
    __shared__ float sws[CC], swb[CC];
    int tid = threadIdx.x;
    for (int i = tid; i < CC*CC; i += 256) sc[i] = par[2*CC + i];
    if (tid < CC) { sws[tid] = par[tid]; swb[tid] = par[CC + tid]; }
    __syncthreads();

    int n = blockIdx.x * 256 + tid;
    const int is_f32 = *flag;

    float msg[CC];
    #pragma unroll
    for (int c = 0; c < CC; c++) {
        msg[c] = fmaf(s2T[(size_t)c*NN + n], sws[c], bil[(size_t)c*NN + n] * swb[c]);
        bil[(size_t)c*NN + n] = 0.f;
    }

    float qv[CC];
    float mx = -1e30f;
    #pragma unroll
    for (int c = 0; c < CC; c++) {
        float pw = 0.f;
        #pragma unroll
        for (int cp = 0; cp < CC; cp++) pw = fmaf(msg[cp], sc[c*CC + cp], pw);
        qv[c] = uf[n*CC + c] - pw;
        mx = fmaxf(mx, qv[c]);
    }

    if (last) {
        #pragma unroll
        for (int c = 0; c < CC; c++) {
            if (is_f32) ((float*)out)[n*CC + c] = qv[c];
            else ((__hip_bfloat16*)out)[n*CC + c] = __float2bfloat16(qv[c]);
        }
    } else {
        float s = 0.f;
        #pragma unroll
        for (int c = 0; c < CC; c++) { qv[c] = fexp(qv[c] - mx); s += qv[c]; }
        float inv = 1.f / s;
        #pragma unroll
        for (int c = 0; c < CC; c++)
            pT[(size_t)c*NN + n] = __float2bfloat16(qv[c] * inv);
    }
}

extern "C" void kernel_launch(void* const* d_in, const int* in_sizes, int n_in,
                              void* d_out, int out_size, void* d_ws, size_t ws_size,
                              hipStream_t stream)
{
    float* ws = (float*)d_ws;
    int*   flag  = (int*)ws;                     // [0..16)
    float* par   = ws + 16;                      // [16..528)
    float* featx = ws + 528;                     // NN*8
    __hip_bfloat16* pT = (__hip_bfloat16*)(ws + 528 + NN*8);  // 32*NN bf16
    float* uf  = ws + 528 + NN*8 + 16*NN;        // NELEM
    float* s2T = uf + NELEM;                     // NELEM (c-major)
    float* bil = s2T + NELEM;                    // NELEM (c-major)
    // total ~ 0.84 MB floats -> ~3.2 MB

    k_sniff<<<1, 1024, 0, stream>>>((const unsigned short*)d_in[0], flag);
    k_prep<<<NN/256, 256, 0, stream>>>(d_in[0], d_in[1], d_in[2], d_in[3], d_in[4],
                                       flag, uf, featx, par, bil, pT);

    for (int it = 0; it < 5; it++) {
        k_work<<<NBB + NBLUR, 256, 0, stream>>>(pT, featx, bil, s2T);
        k_update<<<NN/256, 256, 0, stream>>>(bil, s2T, uf, par, flag,
                                             pT, d_out, (it == 4) ? 1 : 0);
    }
}

// Round 3
// 237.850 us; speedup vs baseline: 1.2112x; 1.1059x over previous
//
#include <hip/hip_runtime.h>
#include <hip/hip_bf16.h>
#include <algorithm>
#include <cmath>

#define HH 96
#define WW 96
#define CC 21
#define NN (HH*WW)          // 9216
#define NELEM (NN*CC)       // 193536
#define RS 20               // blur radius: exp(-400/18)=2e-10 tail, negligible
#define NPAR (2*CC + CC*CC)
#define L2E 1.4426950408889634f
#define MSTEPS 24           // 24 m-rows per chunk (24x16 = 384 px)
#define NBB (36*24)         // 36 n-tiles (16x16) x 24 m-chunks (24x16)
#define NSTRIP 8            // 8 strips of 12 rows
#define NBLUR (CC*NSTRIP)   // 168 blur blocks
#define SROWS 12            // output rows per strip
#define TRUNC2 1225         // 35^2: dropped mass 128*pi*exp(-35^2/128) ~ 0.028 -> ~1e-4 in q
#define BLURKEY 0x10000

typedef short bf16x8 __attribute__((ext_vector_type(8)));
typedef float f32x16 __attribute__((ext_vector_type(16)));

__device__ __forceinline__ float fexp2(float x) { return __builtin_amdgcn_exp2f(x); }
__device__ __forceinline__ float fexp(float x)  { return __builtin_amdgcn_exp2f(x * L2E); }

__device__ __forceinline__ short f2b(float f) {
    __hip_bfloat16 h = __float2bfloat16(f);
    short s; __builtin_memcpy(&s, &h, 2); return s;
}

// ---- dtype sniff: bf16 data never contains exp=0xFF bit patterns; fp32 data's
// low mantissa halves hit it ~0.4% of the time. 32 blocks, each writes its slot.
__global__ void k_sniff(const unsigned short* __restrict__ u16, int* __restrict__ flag32) {
    __shared__ int sfound;
    if (threadIdx.x == 0) sfound = 0;
    __syncthreads();
    const int base = blockIdx.x * (NELEM/32);
    int found = 0;
    for (int i = base + threadIdx.x; i < base + NELEM/32; i += 256) {
        unsigned v = u16[i];
        if ((v & 0x7F80u) == 0x7F80u) found = 1;
    }
    if (found) sfound = 1;
    __syncthreads();
    if (threadIdx.x == 0) flag32[blockIdx.x] = sfound;   // any 1 => fp32 inputs
}

__device__ __forceinline__ int rdflag(const int* __restrict__ flag32) {
    int f = 0;
    #pragma unroll
    for (int i = 0; i < 32; i++) f |= flag32[i];   // uniform -> scalar loads
    return f;
}

// Fused prep: convert u -> uf (fp32 n-major), softmax -> pT (bf16 c-major),
// build featx, convert params, zero bil. Grid 36x256 (one thread per pixel).
__global__ __launch_bounds__(256) void k_prep(
    const void* __restrict__ u, const void* __restrict__ img,
    const void* __restrict__ wS, const void* __restrict__ wB,
    const void* __restrict__ compat, const int* __restrict__ flag32,
    float* __restrict__ uf, float* __restrict__ featx, float* __restrict__ par,
    float* __restrict__ bil, __hip_bfloat16* __restrict__ pT)
{
    const int f = rdflag(flag32);
    const int tid = threadIdx.x;
    const int n = blockIdx.x * 256 + tid;

    if (blockIdx.x == 0) {
        for (int i = tid; i < NPAR; i += 256) {
            const void* src; int j;
            if (i < CC)        { src = wS;     j = i; }
            else if (i < 2*CC) { src = wB;     j = i - CC; }
            else               { src = compat; j = i - 2*CC; }
            par[i] = f ? ((const float*)src)[j]
                       : __bfloat162float(((const __hip_bfloat16*)src)[j]);
        }
    }

    // featx[n]: log2-prescaled symmetric bilateral features
    {
        float c0, c1, c2;
        if (f) { const float* p = (const float*)img;
                 c0 = p[3*n]; c1 = p[3*n+1]; c2 = p[3*n+2]; }
        else   { const __hip_bfloat16* p = (const __hip_bfloat16*)img;
                 c0 = __bfloat162float(p[3*n]); c1 = __bfloat162float(p[3*n+1]);
                 c2 = __bfloat162float(p[3*n+2]); }
        float ym = (float)(n / WW), xm = (float)(n % WW);
        const float sc = 0.15014029f;   // sqrt(2*L2E/128)
        const float cf = 9.6089787f;    // sqrt(64*L2E)
        featx[8*n + 0] = -L2E * (fmaf(ym, ym, xm*xm) * 0.0078125f
                                 + 32.f * (c0*c0 + c1*c1 + c2*c2));
        featx[8*n + 1] = sc * ym;
        featx[8*n + 2] = sc * xm;
        featx[8*n + 3] = cf * c0;
        featx[8*n + 4] = cf * c1;
        featx[8*n + 5] = cf * c2;
        featx[8*n + 6] = 0.f;
        featx[8*n + 7] = 0.f;
    }

    float v[CC];
    float mx = -1e30f;
    #pragma unroll
    for (int c = 0; c < CC; c++) {
        float uv = f ? ((const float*)u)[n*CC + c]
                     : __bfloat162float(((const __hip_bfloat16*)u)[n*CC + c]);
        uf[n*CC + c] = uv;
        v[c] = uv;
        mx = fmaxf(mx, uv);
    }
    float s = 0.f;
    #pragma unroll
    for (int c = 0; c < CC; c++) { v[c] = fexp(v[c] - mx); s += v[c]; }
    float inv = 1.f / s;
    #pragma unroll
    for (int c = 0; c < CC; c++) {
        pT[(size_t)c*NN + n] = __float2bfloat16(v[c] * inv);
        bil[(size_t)c*NN + n] = 0.f;
    }
}

// Fused work kernel driven by a host-sorted work table (LPT order, culled).
// Bilateral items: MFMA over 2D tiles, per-wave precomputed m-row range from
// spatial truncation. Blur items: separable spatial blur.
__global__ __launch_bounds__(256) void k_work(
    const __hip_bfloat16* __restrict__ pT,   // [32][NN] bf16 (rows 21..31 garbage)
    const float* __restrict__ featx,         // [NN][8]
    float* __restrict__ bil,                 // [CC][NN] atomic accum
    float* __restrict__ s2T,                 // [CC][NN] spatial out
    const int* __restrict__ tab)
{
    __shared__ float smem[6176];             // bilateral: 3072; blur: 4992+1152
    const int tid = threadIdx.x;
    const int item = tab[blockIdx.x];

    if (item < BLURKEY) {
        // ---------------- bilateral: bil[c][n] += sum_m pT[c][m] * K(n,m)
        // n-tile: 16x16 pixels. m-chunk: 24 rows x 16 cols; each k-step is one
        // 16-px row segment (contiguous in pT => afrag layout unchanged).
        // D(32c x 32n) = A(32c x 16m) * B(16m x 32n), v_mfma_f32_32x32x16_bf16
        float* lds_h = smem;
        const int wv   = tid >> 6, lane = tid & 63;
        const int quad = lane >> 5, lid = lane & 31;

        const int nt = item >> 5, mc = item & 31;
        const int ny0 = (nt / 6) * 16, nx0 = (nt % 6) * 16;
        const int my0 = (mc & 3) * 24, mx0 = (mc >> 2) * 16;

        const int dx = (mx0 > nx0 + 15) ? mx0 - (nx0 + 15)
                     : ((nx0 > mx0 + 15) ? nx0 - (mx0 + 15) : 0);
        const int lim = TRUNC2 - dx * dx;            // >= 0 (host-culled)
        int T = (int)sqrtf((float)lim);
        T -= (T * T > lim);
        T += ((T + 1) * (T + 1) <= lim);

        // block-union m-row range (for staging)
        int blo = ny0 - T - my0;      blo = blo < 0 ? 0 : blo;
        int bhi = ny0 + 15 + T - my0; bhi = bhi > 23 ? 23 : bhi;

        {   // stage featx rows blo..bhi: [seg][16 px][8 floats]
            float4* dst = (float4*)lds_h;
            for (int i = blo * 32 + tid; i < (bhi + 1) * 32; i += 256) {
                const int seg = i >> 5, off = i & 31;
                dst[i] = ((const float4*)(featx +
                          (size_t)((my0 + seg) * WW + mx0) * 8))[off];
            }
        }
        __syncthreads();

        // per-wave m-row range (wave covers n-rows ny0+4wv .. ny0+4wv+3)
        const int by0 = ny0 + 4 * wv;
        int lo = by0 - T - my0;     lo = lo < 0 ? 0 : lo;
        int hi = by0 + 3 + T - my0; hi = hi > 23 ? 23 : hi;
        if (lo > hi) return;   // wave-uniform; no barriers below

        const int row = lid >> 4, col = lid & 15;
        const int n0 = (by0 + row) * WW + nx0 + col;     // acc0 pixel
        const int n1 = n0 + 2 * WW;                      // acc1 pixel
        const float4 g0a = *(const float4*)(featx + (size_t)n0 * 8);
        const float4 g0b = *(const float4*)(featx + (size_t)n0 * 8 + 4);
        const float4 g1a = *(const float4*)(featx + (size_t)n1 * 8);
        const float4 g1b = *(const float4*)(featx + (size_t)n1 * 8 + 4);

        f32x16 acc0, acc1;
        #pragma unroll
        for (int r = 0; r < 16; r++) { acc0[r] = 0.f; acc1[r] = 0.f; }

        int mg = (my0 + lo) * WW + mx0 + quad * 8;   // afrag global base
        #pragma unroll 1
        for (int step = lo; step <= hi; step++, mg += WW) {
            bf16x8 afrag = *(const bf16x8*)(pT + (size_t)lid * NN + mg);

            const float* h = lds_h + (step * 16 + quad * 8) * 8;
            float kb0[8], kb1[8];
            #pragma unroll
            for (int j = 0; j < 8; j++) {
                float4 ha = *(const float4*)(h + j * 8);
                float4 hb = *(const float4*)(h + j * 8 + 4);
                float s0 = g0a.x + ha.x;
                s0 = fmaf(g0a.y, ha.y, s0);
                s0 = fmaf(g0a.z, ha.z, s0);
                s0 = fmaf(g0a.w, ha.w, s0);
                s0 = fmaf(g0b.x, hb.x, s0);
                s0 = fmaf(g0b.y, hb.y, s0);
                kb0[j] = fexp2(s0);
                float s1 = g1a.x + ha.x;
                s1 = fmaf(g1a.y, ha.y, s1);
                s1 = fmaf(g1a.z, ha.z, s1);
                s1 = fmaf(g1a.w, ha.w, s1);
                s1 = fmaf(g1b.x, hb.x, s1);
                s1 = fmaf(g1b.y, hb.y, s1);
                kb1[j] = fexp2(s1);
            }
            bf16x8 b0, b1;
            #pragma unroll
            for (int j = 0; j < 8; j++) { b0[j] = f2b(kb0[j]); b1[j] = f2b(kb1[j]); }

            acc0 = __builtin_amdgcn_mfma_f32_32x32x16_bf16(afrag, b0, acc0, 0, 0, 0);
            acc1 = __builtin_amdgcn_mfma_f32_32x32x16_bf16(afrag, b1, acc1, 0, 0, 0);
        }

        // D layout: col(n) = lid, row(c) = (r&3) + 8*(r>>2) + 4*quad
        #pragma unroll
        for (int r = 0; r < 16; r++) {
            int c = (r & 3) + 8 * (r >> 2) + 4 * quad;
            if (c < CC) {
                atomicAdd(&bil[(size_t)c * NN + n0], acc0[r]);
                atomicAdd(&bil[(size_t)c * NN + n1], acc1[r]);
            }
        }
    } else {
        // ---------------- spatial blur, one (channel, 12-row strip) per block
        __shared__ float w_s[RS + 1];
        float* A  = smem;            // up to 52 rows x 96
        float* B2 = smem + 4992;     // 12 rows x 96

        const int b2 = item - BLURKEY;
        const int c = b2 % CC;
        const int strip = b2 / CC;
        const int y0 = strip * SROWS;
        const int ylo = (y0 - RS < 0) ? 0 : y0 - RS;
        const int yhi = (y0 + SROWS - 1 + RS > HH - 1) ? HH - 1 : y0 + SROWS - 1 + RS;
        const int nrows = yhi - ylo + 1;

        if (tid <= RS) w_s[tid] = fexp2(-(float)(tid*tid) * (L2E / 18.f));
        const __hip_bfloat16* src = pT + (size_t)c * NN + ylo * WW;
        for (int i = tid; i < nrows * WW; i += 256)
            A[i] = __bfloat162float(src[i]);
        __syncthreads();

        for (int i = tid; i < SROWS * WW; i += 256) {
            const int yo = y0 + i / WW;
            const int x  = i % WW;
            float acc = A[(yo - ylo) * WW + x];
            #pragma unroll
            for (int d = 1; d <= RS; d++) {
                float s = 0.f;
                if (yo - d >= 0)  s += A[(yo - d - ylo) * WW + x];
                if (yo + d < HH)  s += A[(yo + d - ylo) * WW + x];
                acc = fmaf(w_s[d], s, acc);
            }
            B2[i] = acc;
        }
        __syncthreads();

        for (int i = tid; i < SROWS * WW; i += 256) {
            const int r = i / WW, x = i % WW;
            float acc = B2[i];
            #pragma unroll
            for (int d = 1; d <= RS; d++) {
                float s = 0.f;
                if (x - d >= 0)  s += B2[r * WW + x - d];
                if (x + d < WW)  s += B2[r * WW + x + d];
                acc = fmaf(w_s[d], s, acc);
            }
            s2T[(size_t)c * NN + (y0 + r) * WW + x] = acc;
        }
    }
}

// Combine spatial+bilateral, compatibility, q-update, fused softmax -> pT.
// Two lanes per pixel (parity-split over cp) => 288 waves instead of 144.
__global__ __launch_bounds__(256) void k_update(
    float* __restrict__ bil, const float* __restrict__ s2T,
    const float* __restrict__ uf, const float* __restrict__ par,
    const int* __restrict__ flag32,
    __hip_bfloat16* __restrict__ pT, void* __restrict__ out, int last)
{
    __shared__ float sc[CC*CC + 1];
    __shared__ float sws[CC], swb[CC];
    const int tid = threadIdx.x;
    for (int i = tid; i < CC*CC; i += 256) sc[i] = par[2*CC + i];
    if (tid == 0) sc[CC*CC] = 0.f;             // pad for parity-indexed reads
    if (tid < CC) { sws[tid] = par[tid]; swb[tid] = par[CC + tid]; }
    __syncthreads();

    const int half = tid & 1;                  // cp parity owned by this lane
    const int n = blockIdx.x * 128 + (tid >> 1);

    float msg[11];
    #pragma unroll
    for (int k = 0; k < 11; k++) {
        const int cp = 2*k + half;
        if (cp < CC) {
            msg[k] = fmaf(s2T[(size_t)cp*NN + n], sws[cp],
                          bil[(size_t)cp*NN + n] * swb[cp]);
            bil[(size_t)cp*NN + n] = 0.f;
        } else msg[k] = 0.f;
    }

    float pw[CC];
    #pragma unroll
    for (int c = 0; c < CC; c++) {
        float a = msg[0] * sc[c*CC + half];
        #pragma unroll
        for (int k = 1; k < 11; k++)
            a = fmaf(msg[k], sc[c*CC + 2*k + half], a);   // k=10,half=1 -> pad 0
        pw[c] = a;
    }
    #pragma unroll
    for (int c = 0; c < CC; c++)
        pw[c] += __shfl_xor(pw[c], 1, 64);

    float qv[CC];
    float mx = -1e30f;
    #pragma unroll
    for (int c = 0; c < CC; c++) {
        qv[c] = uf[(size_t)n*CC + c] - pw[c];
        mx = fmaxf(mx, qv[c]);
    }

    if (last) {
        const int is_f32 = rdflag(flag32);
        #pragma unroll
        for (int k = 0; k < 11; k++) {
            const int ce = 2*k, co = (k < 10) ? 2*k + 1 : 0;
            float v = half ? qv[co] : qv[ce];          // static reg indices
            const int c = 2*k + half;
            if (c < CC) {
                if (is_f32) ((float*)out)[(size_t)n*CC + c] = v;
                else ((__hip_bfloat16*)out)[(size_t)n*CC + c] = __float2bfloat16(v);
            }
        }
    } else {
        float ex[11]; float ssum = 0.f;
        #pragma unroll
        for (int k = 0; k < 11; k++) {
            const int ce = 2*k, co = (k < 10) ? 2*k + 1 : 0;
            float v = half ? qv[co] : qv[ce];
            float e = fexp(v - mx);
            if (2*k + half < CC) ssum += e;
            ex[k] = e;
        }
        ssum += __shfl_xor(ssum, 1, 64);
        const float inv = 1.f / ssum;
        #pragma unroll
        for (int k = 0; k < 11; k++) {
            const int c = 2*k + half;
            if (c < CC) pT[(size_t)c*NN + n] = __float2bfloat16(ex[k] * inv);
        }
    }
}

extern "C" void kernel_launch(void* const* d_in, const int* in_sizes, int n_in,
                              void* d_out, int out_size, void* d_ws, size_t ws_size,
                              hipStream_t stream)
{
    // ---- static work table (geometry is compile-time): surviving blocks, LPT order
    static int h_tab[NBB + NBLUR];
    static int h_n = 0;
    if (h_n == 0) {
        struct It { int key; int cost; };
        static It its[NBB + NBLUR];
        int m = 0;
        for (int nt = 0; nt < 36; nt++)
            for (int mc = 0; mc < 24; mc++) {
                const int ny0 = (nt / 6) * 16, nx0 = (nt % 6) * 16;
                const int my0 = (mc & 3) * 24, mx0 = (mc >> 2) * 16;
                const int dx = (mx0 > nx0 + 15) ? mx0 - (nx0 + 15)
                             : ((nx0 > mx0 + 15) ? nx0 - (mx0 + 15) : 0);
                const int lim = TRUNC2 - dx * dx;
                if (lim < 0) continue;
                int T = (int)std::sqrt((double)lim);
                while (T * T > lim) T--;
                while ((T + 1) * (T + 1) <= lim) T++;
                int cost = 0;
                for (int wv = 0; wv < 4; wv++) {
                    const int by0 = ny0 + 4 * wv;
                    int lo = by0 - T - my0;     if (lo < 0)  lo = 0;
                    int hi = by0 + 3 + T - my0; if (hi > 23) hi = 23;
                    if (lo <= hi) cost += hi - lo + 1;
                }
                if (cost == 0) continue;
                its[m].key = (nt << 5) | mc; its[m].cost = cost; m++;
            }
        for (int b = 0; b < NBLUR; b++) { its[m].key = BLURKEY + b; its[m].cost = 20; m++; }
        std::sort(its, its + m, [](const It& a, const It& b) { return a.cost > b.cost; });
        for (int i = 0; i < m; i++) h_tab[i] = its[i].key;
        h_n = m;
    }

    float* ws = (float*)d_ws;
    int*   flag32 = (int*)ws;                    // [0..32)
    float* par    = ws + 32;                     // 483 used
    float* featx  = ws + 544;                    // NN*8 = 73728 floats
    __hip_bfloat16* pT = (__hip_bfloat16*)(ws + 74272);   // 32*NN bf16 = 147456 floats
    float* uf  = ws + 74272 + 147456;            // NELEM          (= ws+221728)
    float* s2T = uf + NELEM;                     // NELEM (c-major)
    float* bil = s2T + NELEM;                    // NELEM (c-major)
    int*   d_tab = (int*)(bil + NELEM);          // ~1032 ints; total ~3.2 MB

    hipMemcpyAsync(d_tab, h_tab, h_n * sizeof(int), hipMemcpyHostToDevice, stream);

    k_sniff<<<32, 256, 0, stream>>>((const unsigned short*)d_in[0], flag32);
    k_prep<<<NN/256, 256, 0, stream>>>(d_in[0], d_in[1], d_in[2], d_in[3], d_in[4],
                                       flag32, uf, featx, par, bil, pT);

    for (int it = 0; it < 5; it++) {
        k_work<<<h_n, 256, 0, stream>>>(pT, featx, bil, s2T, d_tab);
        k_update<<<NN/128, 256, 0, stream>>>(bil, s2T, uf, par, flag32,
                                             pT, d_out, (it == 4) ? 1 : 0);
    }
}